// Round 20
// baseline (86.557 us; speedup 1.0000x reference)
//
#include <hip/hip_runtime.h>

#define LRELU(x) ((x) > 0.f ? (x) : 0.01f * (x))

// ws layout (float offsets)
#define H2_OFF    0          // h2t [8][512 co][16 pix]
#define T1_OFF    65536      // [8][512]
#define T2_OFF    69632      // [8][512]
#define PK_OFF    73728      // [8][2048]
#define PB_OFF    90112      // [8][512]
#define WB_OFF    241664     // [8][128][160]
// PART lives in d_out: [32 kc][8 n][9 p][2048 o2] = 4718592 floats (d_out has 16.7M)

// ---------------- kA v4: h (transposed write) + pooled stage 1 ----------------
__global__ __launch_bounds__(256) void kA(const float* __restrict__ style,
    const float* __restrict__ dw1_w, const float* __restrict__ dw1_b,
    const float* __restrict__ pk1_w, const float* __restrict__ pk1_b,
    const float* __restrict__ pb1_w, const float* __restrict__ pb1_b,
    float* __restrict__ h2t, float* __restrict__ t1, float* __restrict__ t2) {
  int b = blockIdx.x;
  int tid = threadIdx.x;
  __shared__ float smem[512];
  int wave = tid >> 6, l = tid & 63;
  float sv[8];
  if (b < 512) {
    int n = b >> 6; int pix = (b >> 2) & 15; int cq = b & 3;
    const float* sp = style + n * 8192 + pix;
#pragma unroll
    for (int j = 0; j < 8; ++j) sv[j] = sp[(8 * l + j) * 16];
    int cobase = cq * 128 + wave * 32;
    float res = (l < 32) ? dw1_b[cobase + l] : 0.f;
#pragma unroll 8
    for (int j = 0; j < 32; ++j) {
      const float4* wr = (const float4*)(dw1_w + (cobase + j) * 512 + 8 * l);
      float4 a = wr[0], c = wr[1];
      float v = a.x*sv[0] + a.y*sv[1] + a.z*sv[2] + a.w*sv[3]
              + c.x*sv[4] + c.y*sv[5] + c.z*sv[6] + c.w*sv[7];
      v += __shfl_xor(v, 1);
      v += __shfl_xor(v, 2);
      v += __shfl_xor(v, 4);
      v += __shfl_xor(v, 8);
      v += __shfl_xor(v, 16);
      v += __shfl_xor(v, 32);
      if (l == j) res += v;
    }
    if (l < 32) h2t[n * 8192 + (cobase + l) * 16 + pix] = LRELU(res);
  } else {
    int b2 = b - 512;
    int cq = b2 & 3; int which = (b2 >> 2) & 1; int n = b2 >> 3;
    for (int ci = tid; ci < 512; ci += 256) {
      const float4* r4 = (const float4*)(style + n * 8192 + ci * 16);
      float4 a = r4[0], bb = r4[1], c = r4[2], d = r4[3];
      smem[ci] = (a.x+a.y+a.z+a.w + bb.x+bb.y+bb.z+bb.w + c.x+c.y+c.z+c.w + d.x+d.y+d.z+d.w) * (1.f/16.f);
    }
    __syncthreads();
#pragma unroll
    for (int j = 0; j < 8; ++j) sv[j] = smem[8 * l + j];
    const float* w  = which ? pb1_w : pk1_w;
    const float* bv = which ? pb1_b : pk1_b;
    int cobase = cq * 128 + wave * 32;
    float* outp = (which ? t2 : t1) + n * 512;
    float res = (l < 32) ? bv[cobase + l] : 0.f;
#pragma unroll 8
    for (int j = 0; j < 32; ++j) {
      const float4* wr = (const float4*)(w + (cobase + j) * 512 + 8 * l);
      float4 a = wr[0], c = wr[1];
      float v = a.x*sv[0] + a.y*sv[1] + a.z*sv[2] + a.w*sv[3]
              + c.x*sv[4] + c.y*sv[5] + c.z*sv[6] + c.w*sv[7];
      v += __shfl_xor(v, 1);
      v += __shfl_xor(v, 2);
      v += __shfl_xor(v, 4);
      v += __shfl_xor(v, 8);
      v += __shfl_xor(v, 16);
      v += __shfl_xor(v, 32);
      if (l == j) res += v;
    }
    if (l < 32) outp[cobase + l] = LRELU(res);
  }
}

// ---------------- kB v6: register-tiled GEMM, W from global, A in LDS ----------------
__global__ __launch_bounds__(256) void kB(const float* __restrict__ h2t,
    const float* __restrict__ dw2_w,
    const float* __restrict__ t1, const float* __restrict__ t2,
    const float* __restrict__ pk2_w, const float* __restrict__ pk2_b,
    const float* __restrict__ pb2_w, const float* __restrict__ pb2_b,
    float* __restrict__ PART, float* __restrict__ pk, float* __restrict__ pb) {
  __shared__ float smem[2592];  // ht: [8 n][16 ci][20] with n-stride 324
  int b = blockIdx.x;
  int tid = threadIdx.x;
  if (b < 512) {
    int bo = b & 15; int kc = b >> 4;
    float* ht = smem;
    {
      int f4 = tid * 2;
#pragma unroll
      for (int j = 0; j < 2; ++j) {
        int fi = f4 + j;
        int n = fi >> 6; int rem = fi & 63; int ci = rem >> 2; int q = rem & 3;
        float4 v = *(const float4*)(h2t + (size_t)n * 8192 + (kc * 16 + ci) * 16 + q * 4);
        *(float4*)&ht[n * 324 + ci * 20 + q * 4] = v;
      }
    }
    __syncthreads();
    int og = tid & 31; int n = tid >> 5;
    const float* hb = &ht[n * 324];
    int o2b = bo * 128 + og * 4;
    const float* wbase = dw2_w + (size_t)o2b * 2048 + kc * 64;
    float acc[9][4];
#pragma unroll
    for (int p = 0; p < 9; ++p)
#pragma unroll
      for (int oj = 0; oj < 4; ++oj) acc[p][oj] = 0.f;
#pragma unroll 2
    for (int ci = 0; ci < 16; ++ci) {
      const float* hr = hb + ci * 20;
      float4 a0 = *(const float4*)(hr);
      float4 a1 = *(const float4*)(hr + 4);
      float4 a2 = *(const float4*)(hr + 8);
      float4 a3 = *(const float4*)(hr + 12);
#pragma unroll
      for (int oj = 0; oj < 4; ++oj) {
        float4 w = *(const float4*)(wbase + (size_t)oj * 2048 + ci * 4);
        acc[0][oj] += w.x*a0.x + w.y*a0.y + w.z*a1.x + w.w*a1.y;
        acc[1][oj] += w.x*a0.y + w.y*a0.z + w.z*a1.y + w.w*a1.z;
        acc[2][oj] += w.x*a0.z + w.y*a0.w + w.z*a1.z + w.w*a1.w;
        acc[3][oj] += w.x*a1.x + w.y*a1.y + w.z*a2.x + w.w*a2.y;
        acc[4][oj] += w.x*a1.y + w.y*a1.z + w.z*a2.y + w.w*a2.z;
        acc[5][oj] += w.x*a1.z + w.y*a1.w + w.z*a2.z + w.w*a2.w;
        acc[6][oj] += w.x*a2.x + w.y*a2.y + w.z*a3.x + w.w*a3.y;
        acc[7][oj] += w.x*a2.y + w.y*a2.z + w.z*a3.y + w.w*a3.z;
        acc[8][oj] += w.x*a2.z + w.y*a2.w + w.z*a3.z + w.w*a3.w;
      }
    }
#pragma unroll
    for (int p = 0; p < 9; ++p) {
      float4 st; st.x = acc[p][0]; st.y = acc[p][1]; st.z = acc[p][2]; st.w = acc[p][3];
      *(float4*)&PART[(size_t)kc * 147456 + (size_t)(n * 9 + p) * 2048 + o2b] = st;
    }
  } else {
    int b2 = b - 512;  // 0..159
    int n = b2 / 20; int t20 = b2 % 20;
    bool isPb = t20 >= 16;
    int cobase = (isPb ? (t20 - 16) : t20) * 128;
    float* s = smem;
    const float* src = (isPb ? t2 : t1) + n * 512;
    for (int i = tid; i < 512; i += 256) s[i] = src[i];
    __syncthreads();
    int wave = tid >> 6, l = tid & 63;
    float sv[8];
#pragma unroll
    for (int j = 0; j < 8; ++j) sv[j] = s[8 * l + j];
    const float* w  = isPb ? pb2_w : pk2_w;
    const float* bv = isPb ? pb2_b : pk2_b;
    int cg = cobase + wave * 32;
    float res = (l < 32) ? bv[cg + l] : 0.f;
#pragma unroll 8
    for (int j = 0; j < 32; ++j) {
      const float4* wr = (const float4*)(w + (cg + j) * 512 + 8 * l);
      float4 a = wr[0], c = wr[1];
      float v = a.x*sv[0] + a.y*sv[1] + a.z*sv[2] + a.w*sv[3]
              + c.x*sv[4] + c.y*sv[5] + c.z*sv[6] + c.w*sv[7];
      v += __shfl_xor(v, 1);
      v += __shfl_xor(v, 2);
      v += __shfl_xor(v, 4);
      v += __shfl_xor(v, 8);
      v += __shfl_xor(v, 16);
      v += __shfl_xor(v, 32);
      if (l == j) res += v;
    }
    if (l < 32) {
      if (isPb) pb[n * 512 + cg + l] = res;
      else      pk[n * 2048 + cg + l] = res;
    }
  }
}

// ---------------- kW v3: weff + pb -> wbuf; sums 32 PART slices inline ----------------
__global__ __launch_bounds__(256) void kW(const float* __restrict__ PART,
    const float* __restrict__ pk, const float* __restrict__ dw2_b,
    const float* __restrict__ pb, float* __restrict__ wbuf) {
  int idx = blockIdx.x * 256 + threadIdx.x;
  if (idx >= 8 * 128 * 160) return;
  int t = idx % 160; int Qn = idx / 160; int Q = Qn & 127; int n = Qn >> 7;
  if (t >= 144) {
    wbuf[idx] = (t < 148) ? pb[n * 512 + Q * 4 + (t - 144)] : 0.f;
    return;
  }
  int o = t & 3; int u = t >> 2; int kx = u % 3; int v = u / 3;
  int i = v & 3; int ky = v >> 2; int p = ky * 3 + kx;
  const float* pkp = pk + n * 2048 + 16 * Q + 4 * o;
  const float* bp  = dw2_b + 16 * Q;
  size_t dbase = (size_t)(n * 9 + p) * 2048 + 16 * Q;
  float sum = 0.f;
#pragma unroll
  for (int j = 0; j < 4; ++j) {
    float dv = bp[4 * j + i];
    size_t off = dbase + 4 * j + i;
#pragma unroll
    for (int s = 0; s < 32; ++s) dv += PART[(size_t)s * 147456 + off];
    sum += pkp[j] * dv;
  }
  wbuf[idx] = sum;
}

// ---------------- kC v11: no-LDS, no-shfl; one-hop loads (b128 + 2 scalar edges) ----------------
// block = (n, Q, 16-row quarter); thread = (r 0..15, e 0..15): 4 o x 4 px
__global__ __launch_bounds__(256) void kC(const float* __restrict__ x,
    const float* __restrict__ wbuf, float* __restrict__ out) {
  int b = blockIdx.x; int rt = b & 3; int Q = (b >> 2) & 127; int n = b >> 9;
  const float* wb = wbuf + (size_t)(n * 128 + Q) * 160;  // block-uniform -> s_load
  const float* base = x + (size_t)(n * 512 + Q * 4) * 4096;
  int e = threadIdx.x & 15;
  int y = rt * 16 + (threadIdx.x >> 4);
  int x0 = 4 * e;
  int xl = (e == 0)  ? 1  : x0 - 1;   // x=-1 -> reflect 1
  int xr = (e == 15) ? 62 : x0 + 4;   // x=64 -> reflect 62
  int ro[3];
#pragma unroll
  for (int ky = 0; ky < 3; ++ky) {
    int ry = y - 1 + ky;
    ry = ry < 0 ? 1 : (ry > 63 ? 62 : ry);
    ro[ky] = ry * 64;
  }
  float acc[4][4];
#pragma unroll
  for (int o = 0; o < 4; ++o) {
    float bv = wb[144 + o];
#pragma unroll
    for (int px = 0; px < 4; ++px) acc[o][px] = bv;
  }
#pragma unroll
  for (int i = 0; i < 4; ++i) {
    const float* ci = base + i * 4096;
    // all 9 loads of this channel are independent: 3 x (b128 + 2 scalars)
    float4 v0_[3]; float vl_[3], vr_[3];
#pragma unroll
    for (int ky = 0; ky < 3; ++ky) {
      const float* rp = ci + ro[ky];
      v0_[ky] = *(const float4*)(rp + x0);
      vl_[ky] = rp[xl];
      vr_[ky] = rp[xr];
    }
#pragma unroll
    for (int ky = 0; ky < 3; ++ky) {
      float va0 = vl_[ky], va1 = v0_[ky].x, va2 = v0_[ky].y, va3 = v0_[ky].z,
            va4 = v0_[ky].w, va5 = vr_[ky];
#pragma unroll
      for (int kx = 0; kx < 3; ++kx) {
        const float* wp = &wb[((ky * 4 + i) * 3 + kx) * 4];
        float w0 = wp[0], w1 = wp[1], w2 = wp[2], w3 = wp[3];
        float xv0 = kx == 0 ? va0 : (kx == 1 ? va1 : va2);
        float xv1 = kx == 0 ? va1 : (kx == 1 ? va2 : va3);
        float xv2 = kx == 0 ? va2 : (kx == 1 ? va3 : va4);
        float xv3 = kx == 0 ? va3 : (kx == 1 ? va4 : va5);
        acc[0][0] += w0 * xv0; acc[0][1] += w0 * xv1; acc[0][2] += w0 * xv2; acc[0][3] += w0 * xv3;
        acc[1][0] += w1 * xv0; acc[1][1] += w1 * xv1; acc[1][2] += w1 * xv2; acc[1][3] += w1 * xv3;
        acc[2][0] += w2 * xv0; acc[2][1] += w2 * xv1; acc[2][2] += w2 * xv2; acc[2][3] += w2 * xv3;
        acc[3][0] += w3 * xv0; acc[3][1] += w3 * xv1; acc[3][2] += w3 * xv2; acc[3][3] += w3 * xv3;
      }
    }
  }
#pragma unroll
  for (int o = 0; o < 4; ++o) {
    float4 st; st.x = acc[o][0]; st.y = acc[o][1]; st.z = acc[o][2]; st.w = acc[o][3];
    *(float4*)&out[(((size_t)(n * 512 + Q * 4 + o)) * 64 + y) * 64 + x0] = st;
  }
}

extern "C" void kernel_launch(void* const* d_in, const int* in_sizes, int n_in,
                              void* d_out, int out_size, void* d_ws, size_t ws_size,
                              hipStream_t stream) {
  const float* style = (const float*)d_in[0];
  const float* pred  = (const float*)d_in[1];
  const float* dw1_w = (const float*)d_in[2];
  const float* dw1_b = (const float*)d_in[3];
  const float* dw2_w = (const float*)d_in[4];
  const float* dw2_b = (const float*)d_in[5];
  const float* pk1_w = (const float*)d_in[6];
  const float* pk1_b = (const float*)d_in[7];
  const float* pk2_w = (const float*)d_in[8];
  const float* pk2_b = (const float*)d_in[9];
  const float* pb1_w = (const float*)d_in[10];
  const float* pb1_b = (const float*)d_in[11];
  const float* pb2_w = (const float*)d_in[12];
  const float* pb2_b = (const float*)d_in[13];
  float* ws  = (float*)d_ws;
  float* h2t = ws + H2_OFF;
  float* t1  = ws + T1_OFF;
  float* t2  = ws + T2_OFF;
  float* pk  = ws + PK_OFF;
  float* pb  = ws + PB_OFF;
  float* wb  = ws + WB_OFF;
  float* out = (float*)d_out;
  float* PART = out;  // scratch in d_out; fully overwritten by kC afterwards

  kA<<<576, 256, 0, stream>>>(style, dw1_w, dw1_b, pk1_w, pk1_b, pb1_w, pb1_b, h2t, t1, t2);
  kB<<<672, 256, 0, stream>>>(h2t, dw2_w, t1, t2, pk2_w, pk2_b, pb2_w, pb2_b, PART, pk, pb);
  kW<<<640, 256, 0, stream>>>(PART, pk, dw2_b, pb, wb);
  kC<<<4096, 256, 0, stream>>>(pred, wb, out);
}

// Round 21
// 74.423 us; speedup vs baseline: 1.1630x; 1.1630x over previous
//
#include <hip/hip_runtime.h>

#define LRELU(x) ((x) > 0.f ? (x) : 0.01f * (x))

// ws layout (float offsets)
#define H2_OFF    0          // h2t [8][512 co][16 pix]
#define T1_OFF    65536      // [8][512]
#define T2_OFF    69632      // [8][512]
#define PK_OFF    73728      // [8][2048]
#define PB_OFF    90112      // [8][512]
#define WB_OFF    241664     // [8][128][160]
// PART lives in d_out: [32 kc][8 n][9 p][2048 o2] = 4718592 floats (d_out has 16.7M)

// ---------------- kA v4: h (transposed write) + pooled stage 1 ----------------
__global__ __launch_bounds__(256) void kA(const float* __restrict__ style,
    const float* __restrict__ dw1_w, const float* __restrict__ dw1_b,
    const float* __restrict__ pk1_w, const float* __restrict__ pk1_b,
    const float* __restrict__ pb1_w, const float* __restrict__ pb1_b,
    float* __restrict__ h2t, float* __restrict__ t1, float* __restrict__ t2) {
  int b = blockIdx.x;
  int tid = threadIdx.x;
  __shared__ float smem[512];
  int wave = tid >> 6, l = tid & 63;
  float sv[8];
  if (b < 512) {
    int n = b >> 6; int pix = (b >> 2) & 15; int cq = b & 3;
    const float* sp = style + n * 8192 + pix;
#pragma unroll
    for (int j = 0; j < 8; ++j) sv[j] = sp[(8 * l + j) * 16];
    int cobase = cq * 128 + wave * 32;
    float res = (l < 32) ? dw1_b[cobase + l] : 0.f;
#pragma unroll 8
    for (int j = 0; j < 32; ++j) {
      const float4* wr = (const float4*)(dw1_w + (cobase + j) * 512 + 8 * l);
      float4 a = wr[0], c = wr[1];
      float v = a.x*sv[0] + a.y*sv[1] + a.z*sv[2] + a.w*sv[3]
              + c.x*sv[4] + c.y*sv[5] + c.z*sv[6] + c.w*sv[7];
      v += __shfl_xor(v, 1);
      v += __shfl_xor(v, 2);
      v += __shfl_xor(v, 4);
      v += __shfl_xor(v, 8);
      v += __shfl_xor(v, 16);
      v += __shfl_xor(v, 32);
      if (l == j) res += v;
    }
    if (l < 32) h2t[n * 8192 + (cobase + l) * 16 + pix] = LRELU(res);
  } else {
    int b2 = b - 512;
    int cq = b2 & 3; int which = (b2 >> 2) & 1; int n = b2 >> 3;
    for (int ci = tid; ci < 512; ci += 256) {
      const float4* r4 = (const float4*)(style + n * 8192 + ci * 16);
      float4 a = r4[0], bb = r4[1], c = r4[2], d = r4[3];
      smem[ci] = (a.x+a.y+a.z+a.w + bb.x+bb.y+bb.z+bb.w + c.x+c.y+c.z+c.w + d.x+d.y+d.z+d.w) * (1.f/16.f);
    }
    __syncthreads();
#pragma unroll
    for (int j = 0; j < 8; ++j) sv[j] = smem[8 * l + j];
    const float* w  = which ? pb1_w : pk1_w;
    const float* bv = which ? pb1_b : pk1_b;
    int cobase = cq * 128 + wave * 32;
    float* outp = (which ? t2 : t1) + n * 512;
    float res = (l < 32) ? bv[cobase + l] : 0.f;
#pragma unroll 8
    for (int j = 0; j < 32; ++j) {
      const float4* wr = (const float4*)(w + (cobase + j) * 512 + 8 * l);
      float4 a = wr[0], c = wr[1];
      float v = a.x*sv[0] + a.y*sv[1] + a.z*sv[2] + a.w*sv[3]
              + c.x*sv[4] + c.y*sv[5] + c.z*sv[6] + c.w*sv[7];
      v += __shfl_xor(v, 1);
      v += __shfl_xor(v, 2);
      v += __shfl_xor(v, 4);
      v += __shfl_xor(v, 8);
      v += __shfl_xor(v, 16);
      v += __shfl_xor(v, 32);
      if (l == j) res += v;
    }
    if (l < 32) outp[cobase + l] = LRELU(res);
  }
}

// ---------------- kB v6: register-tiled GEMM, W from global, A in LDS ----------------
__global__ __launch_bounds__(256) void kB(const float* __restrict__ h2t,
    const float* __restrict__ dw2_w,
    const float* __restrict__ t1, const float* __restrict__ t2,
    const float* __restrict__ pk2_w, const float* __restrict__ pk2_b,
    const float* __restrict__ pb2_w, const float* __restrict__ pb2_b,
    float* __restrict__ PART, float* __restrict__ pk, float* __restrict__ pb) {
  __shared__ float smem[2592];  // ht: [8 n][16 ci][20] with n-stride 324
  int b = blockIdx.x;
  int tid = threadIdx.x;
  if (b < 512) {
    int bo = b & 15; int kc = b >> 4;
    float* ht = smem;
    {
      int f4 = tid * 2;
#pragma unroll
      for (int j = 0; j < 2; ++j) {
        int fi = f4 + j;
        int n = fi >> 6; int rem = fi & 63; int ci = rem >> 2; int q = rem & 3;
        float4 v = *(const float4*)(h2t + (size_t)n * 8192 + (kc * 16 + ci) * 16 + q * 4);
        *(float4*)&ht[n * 324 + ci * 20 + q * 4] = v;
      }
    }
    __syncthreads();
    int og = tid & 31; int n = tid >> 5;
    const float* hb = &ht[n * 324];
    int o2b = bo * 128 + og * 4;
    const float* wbase = dw2_w + (size_t)o2b * 2048 + kc * 64;
    float acc[9][4];
#pragma unroll
    for (int p = 0; p < 9; ++p)
#pragma unroll
      for (int oj = 0; oj < 4; ++oj) acc[p][oj] = 0.f;
#pragma unroll 2
    for (int ci = 0; ci < 16; ++ci) {
      const float* hr = hb + ci * 20;
      float4 a0 = *(const float4*)(hr);
      float4 a1 = *(const float4*)(hr + 4);
      float4 a2 = *(const float4*)(hr + 8);
      float4 a3 = *(const float4*)(hr + 12);
#pragma unroll
      for (int oj = 0; oj < 4; ++oj) {
        float4 w = *(const float4*)(wbase + (size_t)oj * 2048 + ci * 4);
        acc[0][oj] += w.x*a0.x + w.y*a0.y + w.z*a1.x + w.w*a1.y;
        acc[1][oj] += w.x*a0.y + w.y*a0.z + w.z*a1.y + w.w*a1.z;
        acc[2][oj] += w.x*a0.z + w.y*a0.w + w.z*a1.z + w.w*a1.w;
        acc[3][oj] += w.x*a1.x + w.y*a1.y + w.z*a2.x + w.w*a2.y;
        acc[4][oj] += w.x*a1.y + w.y*a1.z + w.z*a2.y + w.w*a2.z;
        acc[5][oj] += w.x*a1.z + w.y*a1.w + w.z*a2.z + w.w*a2.w;
        acc[6][oj] += w.x*a2.x + w.y*a2.y + w.z*a3.x + w.w*a3.y;
        acc[7][oj] += w.x*a2.y + w.y*a2.z + w.z*a3.y + w.w*a3.z;
        acc[8][oj] += w.x*a2.z + w.y*a2.w + w.z*a3.z + w.w*a3.w;
      }
    }
#pragma unroll
    for (int p = 0; p < 9; ++p) {
      float4 st; st.x = acc[p][0]; st.y = acc[p][1]; st.z = acc[p][2]; st.w = acc[p][3];
      *(float4*)&PART[(size_t)kc * 147456 + (size_t)(n * 9 + p) * 2048 + o2b] = st;
    }
  } else {
    int b2 = b - 512;  // 0..159
    int n = b2 / 20; int t20 = b2 % 20;
    bool isPb = t20 >= 16;
    int cobase = (isPb ? (t20 - 16) : t20) * 128;
    float* s = smem;
    const float* src = (isPb ? t2 : t1) + n * 512;
    for (int i = tid; i < 512; i += 256) s[i] = src[i];
    __syncthreads();
    int wave = tid >> 6, l = tid & 63;
    float sv[8];
#pragma unroll
    for (int j = 0; j < 8; ++j) sv[j] = s[8 * l + j];
    const float* w  = isPb ? pb2_w : pk2_w;
    const float* bv = isPb ? pb2_b : pk2_b;
    int cg = cobase + wave * 32;
    float res = (l < 32) ? bv[cg + l] : 0.f;
#pragma unroll 8
    for (int j = 0; j < 32; ++j) {
      const float4* wr = (const float4*)(w + (cg + j) * 512 + 8 * l);
      float4 a = wr[0], c = wr[1];
      float v = a.x*sv[0] + a.y*sv[1] + a.z*sv[2] + a.w*sv[3]
              + c.x*sv[4] + c.y*sv[5] + c.z*sv[6] + c.w*sv[7];
      v += __shfl_xor(v, 1);
      v += __shfl_xor(v, 2);
      v += __shfl_xor(v, 4);
      v += __shfl_xor(v, 8);
      v += __shfl_xor(v, 16);
      v += __shfl_xor(v, 32);
      if (l == j) res += v;
    }
    if (l < 32) {
      if (isPb) pb[n * 512 + cg + l] = res;
      else      pk[n * 2048 + cg + l] = res;
    }
  }
}

// ---------------- kW v3: weff + pb -> wbuf; sums 32 PART slices inline ----------------
__global__ __launch_bounds__(256) void kW(const float* __restrict__ PART,
    const float* __restrict__ pk, const float* __restrict__ dw2_b,
    const float* __restrict__ pb, float* __restrict__ wbuf) {
  int idx = blockIdx.x * 256 + threadIdx.x;
  if (idx >= 8 * 128 * 160) return;
  int t = idx % 160; int Qn = idx / 160; int Q = Qn & 127; int n = Qn >> 7;
  if (t >= 144) {
    wbuf[idx] = (t < 148) ? pb[n * 512 + Q * 4 + (t - 144)] : 0.f;
    return;
  }
  int o = t & 3; int u = t >> 2; int kx = u % 3; int v = u / 3;
  int i = v & 3; int ky = v >> 2; int p = ky * 3 + kx;
  const float* pkp = pk + n * 2048 + 16 * Q + 4 * o;
  const float* bp  = dw2_b + 16 * Q;
  size_t dbase = (size_t)(n * 9 + p) * 2048 + 16 * Q;
  float sum = 0.f;
#pragma unroll
  for (int j = 0; j < 4; ++j) {
    float dv = bp[4 * j + i];
    size_t off = dbase + 4 * j + i;
#pragma unroll
    for (int s = 0; s < 32; ++s) dv += PART[(size_t)s * 147456 + off];
    sum += pkp[j] * dv;
  }
  wbuf[idx] = sum;
}

// ---------------- kC v12: no-LDS, shfl edges, FULL 12-load upfront prefetch ----------------
// block = (n, Q, 16-row quarter); thread = (r 0..15, e 0..15): 4 o x 4 px
__global__ __launch_bounds__(256) void kC(const float* __restrict__ x,
    const float* __restrict__ wbuf, float* __restrict__ out) {
  int b = blockIdx.x; int rt = b & 3; int Q = (b >> 2) & 127; int n = b >> 9;
  const float* wb = wbuf + (size_t)(n * 128 + Q) * 160;  // block-uniform -> s_load
  const float* base = x + (size_t)(n * 512 + Q * 4) * 4096;
  int e = threadIdx.x & 15;
  int y = rt * 16 + (threadIdx.x >> 4);
  int x0 = 4 * e;
  int ro[3];
#pragma unroll
  for (int ky = 0; ky < 3; ++ky) {
    int ry = y - 1 + ky;
    ry = ry < 0 ? 1 : (ry > 63 ? 62 : ry);
    ro[ky] = ry * 64;
  }
  // issue ALL 12 independent b128 loads up front (max MLP, single drain)
  float4 v[4][3];
#pragma unroll
  for (int i = 0; i < 4; ++i)
#pragma unroll
    for (int ky = 0; ky < 3; ++ky)
      v[i][ky] = *(const float4*)(base + i * 4096 + ro[ky] + x0);
  float acc[4][4];
#pragma unroll
  for (int o = 0; o < 4; ++o) {
    float bv = wb[144 + o];
#pragma unroll
    for (int px = 0; px < 4; ++px) acc[o][px] = bv;
  }
#pragma unroll
  for (int i = 0; i < 4; ++i) {
#pragma unroll
    for (int ky = 0; ky < 3; ++ky) {
      float vl = __shfl_up(v[i][ky].w, 1, 16);    // lane e-1's x0+3 = x0-1
      float vr = __shfl_down(v[i][ky].x, 1, 16);  // lane e+1's x0+4
      if (e == 0)  vl = v[i][ky].y;               // x=-1 -> reflect 1
      if (e == 15) vr = v[i][ky].z;               // x=64 -> reflect 62
      float va0 = vl, va1 = v[i][ky].x, va2 = v[i][ky].y, va3 = v[i][ky].z,
            va4 = v[i][ky].w, va5 = vr;
#pragma unroll
      for (int kx = 0; kx < 3; ++kx) {
        const float* wp = &wb[((ky * 4 + i) * 3 + kx) * 4];
        float w0 = wp[0], w1 = wp[1], w2 = wp[2], w3 = wp[3];
        float xv0 = kx == 0 ? va0 : (kx == 1 ? va1 : va2);
        float xv1 = kx == 0 ? va1 : (kx == 1 ? va2 : va3);
        float xv2 = kx == 0 ? va2 : (kx == 1 ? va3 : va4);
        float xv3 = kx == 0 ? va3 : (kx == 1 ? va4 : va5);
        acc[0][0] += w0 * xv0; acc[0][1] += w0 * xv1; acc[0][2] += w0 * xv2; acc[0][3] += w0 * xv3;
        acc[1][0] += w1 * xv0; acc[1][1] += w1 * xv1; acc[1][2] += w1 * xv2; acc[1][3] += w1 * xv3;
        acc[2][0] += w2 * xv0; acc[2][1] += w2 * xv1; acc[2][2] += w2 * xv2; acc[2][3] += w2 * xv3;
        acc[3][0] += w3 * xv0; acc[3][1] += w3 * xv1; acc[3][2] += w3 * xv2; acc[3][3] += w3 * xv3;
      }
    }
  }
#pragma unroll
  for (int o = 0; o < 4; ++o) {
    float4 st; st.x = acc[o][0]; st.y = acc[o][1]; st.z = acc[o][2]; st.w = acc[o][3];
    *(float4*)&out[(((size_t)(n * 512 + Q * 4 + o)) * 64 + y) * 64 + x0] = st;
  }
}

extern "C" void kernel_launch(void* const* d_in, const int* in_sizes, int n_in,
                              void* d_out, int out_size, void* d_ws, size_t ws_size,
                              hipStream_t stream) {
  const float* style = (const float*)d_in[0];
  const float* pred  = (const float*)d_in[1];
  const float* dw1_w = (const float*)d_in[2];
  const float* dw1_b = (const float*)d_in[3];
  const float* dw2_w = (const float*)d_in[4];
  const float* dw2_b = (const float*)d_in[5];
  const float* pk1_w = (const float*)d_in[6];
  const float* pk1_b = (const float*)d_in[7];
  const float* pk2_w = (const float*)d_in[8];
  const float* pk2_b = (const float*)d_in[9];
  const float* pb1_w = (const float*)d_in[10];
  const float* pb1_b = (const float*)d_in[11];
  const float* pb2_w = (const float*)d_in[12];
  const float* pb2_b = (const float*)d_in[13];
  float* ws  = (float*)d_ws;
  float* h2t = ws + H2_OFF;
  float* t1  = ws + T1_OFF;
  float* t2  = ws + T2_OFF;
  float* pk  = ws + PK_OFF;
  float* pb  = ws + PB_OFF;
  float* wb  = ws + WB_OFF;
  float* out = (float*)d_out;
  float* PART = out;  // scratch in d_out; fully overwritten by kC afterwards

  kA<<<576, 256, 0, stream>>>(style, dw1_w, dw1_b, pk1_w, pk1_b, pb1_w, pb1_b, h2t, t1, t2);
  kB<<<672, 256, 0, stream>>>(h2t, dw2_w, t1, t2, pk2_w, pk2_b, pb2_w, pb2_b, PART, pk, pb);
  kW<<<640, 256, 0, stream>>>(PART, pk, dw2_b, pb, wb);
  kC<<<4096, 256, 0, stream>>>(pred, wb, out);
}